// Round 4
// baseline (117.773 us; speedup 1.0000x reference)
//
#include <hip/hip_runtime.h>

// Beam-search gather_tree for [max_len=256, batch=4096, beam=8] int32.
//
// One thread per (batch, beam) chain; 64-thread blocks = 8 batches/wave.
// Backtrace loop: each lane loads its OWN beam element of step_ids/parent_ids
// (coalesced 256B/wave), then gathers [b, cur] via __shfl within the 8-lane
// batch group. first_end (first t where token==end) is tracked on the fly
// (t descending -> final value is the min), which directly gives the
// end-masking boundary AND the lengths output.
// Tokens are staged in a [256][65]-padded LDS tile; the write phase
// transposes to the [b][j][t] output layout with coalesced stores.
//
// unroll 16: Little's law — per-CU BW share 24.6 GB/s x 375 ns HBM latency
// needs ~9.2 KB in flight; 32 dword loads/wave x 256 B x 2 waves/CU = 16 KB.

constexpr int MAX_LEN = 256;
constexpr int BATCH   = 4096;
constexpr int BEAM    = 8;
constexpr int NCHAIN  = BATCH * BEAM;   // 32768
constexpr int PITCH   = 65;             // +1 pad: conflict-free both phases

__global__ __launch_bounds__(64)
void gather_tree_kernel(const int* __restrict__ step_ids,
                        const int* __restrict__ parent_ids,
                        const int* __restrict__ seq_lens,
                        const int* __restrict__ end_id_p,
                        int* __restrict__ out_ids,
                        int* __restrict__ out_lens)
{
    __shared__ int toks[MAX_LEN * PITCH];   // 66,560 B

    const int lane = threadIdx.x;                 // 0..63
    const int bj0  = blockIdx.x * 64;             // first chain of this block
    const int bj   = bj0 + lane;                  // this lane's chain
    const int j    = bj & (BEAM - 1);             // own beam index
    const int grp  = lane & ~(BEAM - 1);          // base lane of batch group
    const int end_tok = *end_id_p;

    // msl = min(max over beams of seq_lens[b][*], MAX_LEN), per batch group
    int sl = seq_lens[bj];
    sl = max(sl, __shfl_xor(sl, 1));
    sl = max(sl, __shfl_xor(sl, 2));
    sl = max(sl, __shfl_xor(sl, 4));
    const int msl = min(sl, MAX_LEN);

    int cur = j;
    int first_end = MAX_LEN;
    int idx = (MAX_LEN - 1) * NCHAIN + bj;

    #pragma unroll 16
    for (int t = MAX_LEN - 1; t >= 0; --t, idx -= NCHAIN) {
        int s = step_ids[idx];     // own beam element (coalesced)
        int p = parent_ids[idx];   // own beam element (coalesced)
        int src = grp + cur;       // gather lane for [b, cur]
        int tokg = __shfl(s, src);
        int pg   = __shfl(p, src);
        bool active = t < msl;
        int tok = active ? tokg : end_tok;
        cur = active ? (pg & (BEAM - 1)) : cur;
        if (tok == end_tok) first_end = t;   // t descending -> ends at min t
        toks[t * PITCH + lane] = tok;
    }

    __syncthreads();

    // Transpose write: chain c's 256 tokens, lanes cover t = k*64 + lane
    // (coalesced 256B global stores; LDS bank = (lane+c)%32 -> 2-way only)
    for (int c = 0; c < 64; ++c) {
        int fe = __shfl(first_end, c);
        int obase = (bj0 + c) * MAX_LEN;
        #pragma unroll
        for (int k = 0; k < 4; ++k) {
            int t = k * 64 + lane;
            int v = toks[t * PITCH + c];
            out_ids[obase + t] = (t < fe) ? v : end_tok;
        }
    }

    out_lens[bj] = first_end;   // lengths == index of first end token
}

extern "C" void kernel_launch(void* const* d_in, const int* in_sizes, int n_in,
                              void* d_out, int out_size, void* d_ws, size_t ws_size,
                              hipStream_t stream)
{
    const int* step_ids   = (const int*)d_in[0];  // output_ids [256,4096,8]
    const int* parent_ids = (const int*)d_in[1];  // parent_ids [256,4096,8]
    const int* seq_lens   = (const int*)d_in[2];  // out_seq_lens [4096,8]
    const int* end_id     = (const int*)d_in[3];  // scalar end_id

    int* out_ids  = (int*)d_out;                          // [4096,8,256]
    int* out_lens = (int*)d_out + MAX_LEN * NCHAIN;       // [4096,8]

    gather_tree_kernel<<<NCHAIN / 64, 64, 0, stream>>>(
        step_ids, parent_ids, seq_lens, end_id, out_ids, out_lens);
}

// Round 6
// 109.556 us; speedup vs baseline: 1.0750x; 1.0750x over previous
//
#include <hip/hip_runtime.h>

// Beam-search gather_tree, segment-composition design.
// [max_len=256, batch=4096, beam=8] int32 -> ids [4096,8,256] + lengths [4096,8].
//
// Block = 256 threads (4 waves), owns 64 chains (8 batches x 8 beams).
// Wave w owns t-segment [64w, 64w+64). Grid = 512 blocks -> 8 waves/CU
// (vs 2 waves/CU in the single-wave baseline, which ran ~41us vs 15us roofline).
//
// Phase A (parallel over segments): lane = (b_loc, h) tracks hypothesis
// "entered segment top in beam h". Per step: build packed 8x3-bit parent map
// with 3 chain-independent __shfl_xor, then chain step = 2 VALU ops
// (cur = (map >> 3*cur) & 7; inactive t uses the identity map). The 3-bit cur
// history is packed 8 steps/dword into LDS; step_ids staged into s_tile;
// segment exit map (8->8) packed and stored.
// Phase C: entry state per chain = compose <=3 higher-segment maps; wave w
// resolves tokens for its own 64 rows IN PLACE (wave-lockstep read->write, rows
// are wave-exclusive), tracks per-segment first_end; barrier; global first_end
// = min over segments; transpose-write with coalesced 256B stores.

constexpr int MAX_LEN = 256;
constexpr int BATCH   = 4096;
constexpr int BEAM    = 8;
constexpr int NCHAIN  = BATCH * BEAM;     // 32768
constexpr int PITCH   = 65;               // bank-conflict pad
constexpr unsigned ID_MAP = 0xFAC688u;    // field j holds j (identity 8->8 map)

__global__ __launch_bounds__(256)
void gather_tree_kernel(const int* __restrict__ step_ids,
                        const int* __restrict__ parent_ids,
                        const int* __restrict__ seq_lens,
                        const int* __restrict__ end_id_p,
                        int* __restrict__ out_ids,
                        int* __restrict__ out_lens)
{
    __shared__ int      s_tile[MAX_LEN * PITCH]; // 66,560 B: staged tokens, then resolved toks
    __shared__ unsigned hist[4 * 8 * 64];        // 8,192 B: [w][word][lane] 8x3-bit cur history
    __shared__ unsigned segmap[4 * 8];           //   128 B: [w][b_loc] packed exit map
    __shared__ int      fe_buf[4 * 64];          // 1,024 B: [w][chain] local first_end
    // total 75,904 B -> 2 blocks/CU

    const int tid   = threadIdx.x;
    const int w     = tid >> 6;          // segment / wave id, 0..3
    const int lane  = tid & 63;
    const int b_loc = lane >> 3;         // batch within block, 0..7
    const int h     = lane & 7;          // phase A: hypothesis; phase C: own beam j
    const int bj0   = blockIdx.x * 64;   // first chain of this block
    const int tbase = w * 64;
    const int end_tok = *end_id_p;

    // msl = min(max over beams of seq_lens[b], MAX_LEN), uniform per 8-lane group
    int sl = seq_lens[bj0 + lane];
    sl = max(sl, __shfl_xor(sl, 1));
    sl = max(sl, __shfl_xor(sl, 2));
    sl = max(sl, __shfl_xor(sl, 4));
    const int msl = min(sl, MAX_LEN);

    // ---------------- Phase A: per-segment hypothesis trace ----------------
    int cur = h;                          // state entering the segment top
    for (int kb = 56; kb >= 0; kb -= 8) {
        unsigned hw = 0;
        #pragma unroll
        for (int i = 7; i >= 0; --i) {
            const int t = tbase + kb + i;
            const int gidx = t * NCHAIN + bj0 + lane;     // own-beam, coalesced
            int s = step_ids[gidx];
            int p = parent_ids[gidx];
            s_tile[t * PITCH + lane] = s;                 // bank (t+lane)%32: 2-way, free
            unsigned m = (unsigned)(p & 7) << (3 * h);    // build packed map (chain-independent)
            m |= (unsigned)__shfl_xor((int)m, 1);
            m |= (unsigned)__shfl_xor((int)m, 2);
            m |= (unsigned)__shfl_xor((int)m, 4);
            const unsigned me = (t < msl) ? m : ID_MAP;   // inactive step = identity
            hw |= (unsigned)cur << (3 * i);               // record cur BEFORE update
            cur = (me >> (3 * cur)) & 7;                  // chain step: 2 VALU ops
        }
        hist[(w * 8 + (kb >> 3)) * 64 + lane] = hw;
    }
    // pack exit map F_w : entry-hyp -> exit state
    unsigned fm = (unsigned)cur << (3 * h);
    fm |= (unsigned)__shfl_xor((int)fm, 1);
    fm |= (unsigned)__shfl_xor((int)fm, 2);
    fm |= (unsigned)__shfl_xor((int)fm, 4);
    if (h == 0) segmap[w * 8 + b_loc] = fm;

    __syncthreads();

    // ---------------- Phase C1: resolve tokens for own segment ----------------
    // entry state of chain j=h into segment w = F_{w+1}(F_{w+2}(...F_3(j)))
    int e = h;
    for (int ww = 3; ww > w; --ww)
        e = (segmap[ww * 8 + b_loc] >> (3 * e)) & 7;

    int fe = MAX_LEN;
    for (int kb = 0; kb < 64; kb += 8) {
        const unsigned hw = hist[(w * 8 + (kb >> 3)) * 64 + b_loc * 8 + e];
        #pragma unroll
        for (int i = 0; i < 8; ++i) {
            const int t = tbase + kb + i;
            const int c = (hw >> (3 * i)) & 7;            // cur_before at step t
            int tok = s_tile[t * PITCH + b_loc * 8 + c];
            tok = (t < msl) ? tok : end_tok;
            if (tok == end_tok) fe = min(fe, t);
            s_tile[t * PITCH + lane] = tok;               // in-place: row t is wave-exclusive,
        }                                                 // read->write lockstep within wave
    }
    fe_buf[w * 64 + lane] = fe;

    __syncthreads();

    // ---------------- Phase C2: global first_end + transpose write ----------------
    const int feg = min(min(fe_buf[lane], fe_buf[64 + lane]),
                        min(fe_buf[128 + lane], fe_buf[192 + lane]));
    if (w == 0) out_lens[bj0 + lane] = feg;               // lengths == first_end

    const int t = tbase + lane;                           // wave w writes its own 64 rows
    for (int c0 = 0; c0 < 64; ++c0) {
        const int fec = __shfl(feg, c0);
        const int v = s_tile[t * PITCH + c0];             // bank (lane+c0)%32: 2-way
        out_ids[(bj0 + c0) * MAX_LEN + t] = (t < fec) ? v : end_tok;  // 256B coalesced
    }
}

extern "C" void kernel_launch(void* const* d_in, const int* in_sizes, int n_in,
                              void* d_out, int out_size, void* d_ws, size_t ws_size,
                              hipStream_t stream)
{
    const int* step_ids   = (const int*)d_in[0];  // output_ids [256,4096,8]
    const int* parent_ids = (const int*)d_in[1];  // parent_ids [256,4096,8]
    const int* seq_lens   = (const int*)d_in[2];  // out_seq_lens [4096,8]
    const int* end_id     = (const int*)d_in[3];  // scalar end_id

    int* out_ids  = (int*)d_out;                          // [4096,8,256]
    int* out_lens = (int*)d_out + MAX_LEN * NCHAIN;       // [4096,8]

    gather_tree_kernel<<<NCHAIN / 64, 256, 0, stream>>>(
        step_ids, parent_ids, seq_lens, end_id, out_ids, out_lens);
}

// Round 8
// 105.056 us; speedup vs baseline: 1.1211x; 1.0428x over previous
//
#include <hip/hip_runtime.h>

// Beam-search gather_tree, segment-composition v2.
// [max_len=256, batch=4096, beam=8] int32 -> ids [4096,8,256] + lengths [4096,8].
//
// Block = 1024 threads (16 waves), owns 64 chains (8 batches x 8 beams).
// Wave w owns t-segment [16w, 16w+16). Grid = 512 blocks; LDS 79.4 KB ->
// 2 blocks/CU -> 32 waves/CU (CU max), vs 8 waves/CU in v1.
//
// Phase A: lane (b_loc,h) tracks hypothesis "entered segment top in beam h".
// Per step: ONE ds_bpermute (pg = shfl(p, b8+cur)) replaces v1's 3-shfl
// packed-map build (DS-op hot spot); 3-bit cur history packed 8/dword in LDS;
// raw tokens staged to s_tile; per-segment 8->8 exit map packed once at end.
// Phase C1: chain entry state = compose higher-segment maps (<=15 LDS
// broadcast reads); resolve own segment's tokens in place (wave-exclusive
// rows, read-instr precedes write-instr in lockstep); per-segment first_end.
// Phase C2: global first_end = min over 16 segments; wave w transpose-writes
// chains [4w,4w+4) with coalesced 256B stores.

constexpr int MAX_LEN = 256;
constexpr int BATCH   = 4096;
constexpr int BEAM    = 8;
constexpr int NCHAIN  = BATCH * BEAM;   // 32768
constexpr int PITCH   = 65;             // bank-conflict pad (2-way max everywhere)
constexpr int NW      = 16;             // waves per block
constexpr int SEG     = 16;             // t-steps per segment

__global__ __launch_bounds__(1024)
void gather_tree_kernel(const int* __restrict__ step_ids,
                        const int* __restrict__ parent_ids,
                        const int* __restrict__ seq_lens,
                        const int* __restrict__ end_id_p,
                        int* __restrict__ out_ids,
                        int* __restrict__ out_lens)
{
    __shared__ int      s_tile[MAX_LEN * PITCH]; // 66,560 B: raw then resolved tokens
    __shared__ unsigned hist[NW * 2 * 64];       //  8,192 B: [seg][word][hyp] 8x3-bit cur
    __shared__ unsigned segmap[NW * 8];          //    512 B: [seg][b_loc] packed exit map
    __shared__ int      fe_buf[NW * 64];         //  4,096 B: [seg][chain] local first_end
    // total 79,360 B -> 2 blocks/CU = 32 waves/CU

    const int tid   = threadIdx.x;
    const int w     = tid >> 6;          // wave id == segment id, 0..15
    const int lane  = tid & 63;
    const int b_loc = lane >> 3;         // batch within block, 0..7
    const int h     = lane & 7;          // phase A: hypothesis; phase C: own beam j
    const int bj0   = blockIdx.x * 64;   // first chain of this block
    const int tbase = w * SEG;
    const int end_tok = *end_id_p;

    // msl = min(max over beams of seq_lens[b], MAX_LEN), uniform per 8-lane group
    int sl = seq_lens[bj0 + lane];
    sl = max(sl, __shfl_xor(sl, 1));
    sl = max(sl, __shfl_xor(sl, 2));
    sl = max(sl, __shfl_xor(sl, 4));
    const int msl = min(sl, MAX_LEN);

    // ---------------- Phase A: per-segment hypothesis trace ----------------
    int cur = h;                          // state entering the segment top
    for (int kb = SEG - 8; kb >= 0; kb -= 8) {
        unsigned hw = 0;
        #pragma unroll
        for (int i = 7; i >= 0; --i) {
            const int t = tbase + kb + i;
            const int g = t * NCHAIN + bj0 + lane;       // own-beam, coalesced 256B
            int s = step_ids[g];
            int p = parent_ids[g];
            s_tile[t * PITCH + lane] = s;                // raw token stage
            int pg = __shfl(p, b_loc * 8 + cur);         // 1 ds_bpermute (vs 3 swizzles)
            hw |= (unsigned)cur << (3 * i);              // record cur BEFORE update
            cur = (t < msl) ? (pg & 7) : cur;
        }
        hist[(w * 2 + (kb >> 3)) * 64 + lane] = hw;
    }
    // pack exit map F_w : entry-hyp -> exit state (once per segment)
    unsigned fm = (unsigned)cur << (3 * h);
    fm |= (unsigned)__shfl_xor((int)fm, 1);
    fm |= (unsigned)__shfl_xor((int)fm, 2);
    fm |= (unsigned)__shfl_xor((int)fm, 4);
    if (h == 0) segmap[w * 8 + b_loc] = fm;

    __syncthreads();

    // ---------------- Phase C1: resolve own segment (lane = chain) ----------------
    // entry state of chain j=h into segment w = F_{w+1}(F_{w+2}(...F_15(j)))
    int e = h;
    for (int ww = NW - 1; ww > w; --ww)
        e = (segmap[ww * 8 + b_loc] >> (3 * e)) & 7;

    int fe = MAX_LEN;
    for (int kb = 0; kb < SEG; kb += 8) {
        const unsigned hw = hist[(w * 2 + (kb >> 3)) * 64 + b_loc * 8 + e];
        #pragma unroll
        for (int i = 0; i < 8; ++i) {
            const int t = tbase + kb + i;
            const int c = (hw >> (3 * i)) & 7;           // cur_before at step t
            int tok = s_tile[t * PITCH + b_loc * 8 + c]; // <=2-way bank alias (free)
            tok = (t < msl) ? tok : end_tok;
            if (tok == end_tok) fe = min(fe, t);
            s_tile[t * PITCH + lane] = tok;              // in-place: rows segment-exclusive
        }
    }
    fe_buf[w * 64 + lane] = fe;

    __syncthreads();

    // ---------------- Phase C2: global first_end + transpose write ----------------
    int feg = fe_buf[lane];
    #pragma unroll
    for (int w2 = 1; w2 < NW; ++w2) feg = min(feg, fe_buf[w2 * 64 + lane]);
    if (w == 0) out_lens[bj0 + lane] = feg;              // lengths == first_end

    // wave w writes chains [4w, 4w+4): per chain, lanes cover t (256B coalesced)
    #pragma unroll
    for (int cc = 0; cc < 4; ++cc) {
        const int c = w * 4 + cc;
        const int fec = __shfl(feg, c);                  // uniform src -> readlane
        #pragma unroll
        for (int k = 0; k < 4; ++k) {
            const int t = k * 64 + lane;
            const int v = s_tile[t * PITCH + c];         // stride-65 rows: conflict-free
            out_ids[(bj0 + c) * MAX_LEN + t] = (t < fec) ? v : end_tok;
        }
    }
}

extern "C" void kernel_launch(void* const* d_in, const int* in_sizes, int n_in,
                              void* d_out, int out_size, void* d_ws, size_t ws_size,
                              hipStream_t stream)
{
    const int* step_ids   = (const int*)d_in[0];  // output_ids [256,4096,8]
    const int* parent_ids = (const int*)d_in[1];  // parent_ids [256,4096,8]
    const int* seq_lens   = (const int*)d_in[2];  // out_seq_lens [4096,8]
    const int* end_id     = (const int*)d_in[3];  // scalar end_id

    int* out_ids  = (int*)d_out;                          // [4096,8,256]
    int* out_lens = (int*)d_out + MAX_LEN * NCHAIN;       // [4096,8]

    gather_tree_kernel<<<NCHAIN / 64, 1024, 0, stream>>>(
        step_ids, parent_ids, seq_lens, end_id, out_ids, out_lens);
}